// Round 8
// baseline (129.052 us; speedup 1.0000x reference)
//
#include <hip/hip_runtime.h>

#define N_NODES 8192
#define DIM     128
#define N_COMM  100
#define MARGIN  1.0f
#define NPOSBLK (N_COMM * 4)

// Single-bf16 Gram (round-7 win, absmax 0.0). Round-8: minneg reads MFMA
// fragments DIRECTLY from global (xh = 2 MB, L2-resident on every XCD) —
// no LDS staging, no K-loop barriers, no ds_read bank conflicts. LDS holds
// only the epilogue reduction overlays (35840 B -> 4 blocks/CU).
// (Round-5 lesson: cooperative grid.sync >>100us on MI355X — multi-kernel +
// device-scope done-counter merge for pos+finalize is the fastest structure.)
#define RP_STR   68               // row-min partial stride (floats)

typedef __attribute__((ext_vector_type(8)))  short bf16x8;
typedef __attribute__((ext_vector_type(16))) float f32x16;

__device__ inline unsigned short f32_to_bf16_rne(float f) {
    unsigned u = __float_as_uint(f);
    unsigned r = u + 0x7fffu + ((u >> 16) & 1u);
    return (unsigned short)(r >> 16);
}

// ---------------------------------------------------------------------------
// Kernel 0 (merged): blocks 0..2047 = bf16 convert + row sq norms + min_d2
// init (wave per row); block 2048 = community bucketing + counter zeroing.
__global__ __launch_bounds__(256)
void prep_kernel(const float* __restrict__ x,
                 const int* __restrict__ comm,
                 unsigned short* __restrict__ xh,
                 float* __restrict__ sq,
                 unsigned int* __restrict__ min_d2,
                 int* __restrict__ offs,
                 int* __restrict__ members,
                 double* __restrict__ psum,
                 unsigned int* __restrict__ pcnt,
                 unsigned int* __restrict__ done) {
    __shared__ int scnt[N_COMM];
    __shared__ int scur[N_COMM];
    const int tid = threadIdx.x;

    if (blockIdx.x < 2048) {
        int row  = blockIdx.x * 4 + (tid >> 6);
        int lane = tid & 63;
        const float* p = x + (size_t)row * DIM;
        float v0 = p[lane], v1 = p[lane + 64];
        unsigned short h0 = f32_to_bf16_rne(v0), h1 = f32_to_bf16_rne(v1);
        size_t base = (size_t)row * DIM;
        xh[base + lane] = h0;  xh[base + 64 + lane] = h1;
        float s = v0 * v0 + v1 * v1;   // sq stays fp32-exact
        #pragma unroll
        for (int off = 32; off > 0; off >>= 1) s += __shfl_down(s, off);
        if (lane == 0) {
            sq[row] = s;
            min_d2[row] = 0x7f800000u;   // +inf bits
        }
        return;
    }

    // ---- bucketing block
    if (tid < N_COMM) {
        scnt[tid] = 0;
        psum[tid] = 0.0;      // pos kernel accumulates -> zero each launch
        pcnt[tid] = 0u;
    }
    if (tid == 0) *done = 0u;
    __syncthreads();
    for (int i = tid; i < N_NODES; i += 256) atomicAdd(&scnt[comm[i]], 1);
    __syncthreads();
    if (tid == 0) {
        int acc = 0;
        for (int c = 0; c < N_COMM; ++c) { scur[c] = acc; offs[c] = acc; acc += scnt[c]; }
        offs[N_COMM] = acc;
    }
    __syncthreads();
    for (int i = tid; i < N_NODES; i += 256) {
        int p = atomicAdd(&scur[comm[i]], 1);
        members[p] = i;
    }
}

// ---------------------------------------------------------------------------
// Kernel 1: MFMA X·X^T (plain bf16), exact triangular grid (2080 blocks),
// fragments loaded DIRECTLY from global (L2-hot), col-min AND row-min.
// C/D layout (m74/m101): col = lane&31, row = (reg&3) + 8*(reg>>2) + 4*(lane>>5).
// A/B frag layout for 32x32x16: row/col = lane&31, k = 8*(lane>>5)+i.
__global__ __launch_bounds__(256, 4)
void minneg_mfma_kernel(const unsigned short* __restrict__ xh,
                        const int* __restrict__ comm,
                        const float* __restrict__ sq,
                        unsigned int* __restrict__ min_d2) {
    __shared__ __align__(16) float rowpart[128][RP_STR];   // 34816 B
    __shared__ float colpart[128][2];                      //  1024 B

    // linear -> lower-triangle (bx >= by)
    const int b = blockIdx.x;
    int bx = (int)((sqrtf(8.f * (float)b + 1.f) - 1.f) * 0.5f);
    while ((bx + 1) * (bx + 2) / 2 <= b) ++bx;
    while (bx * (bx + 1) / 2 > b) --bx;
    const int by = b - bx * (bx + 1) / 2;

    const int tid  = threadIdx.x;
    const int lane = tid & 63;
    const int w    = tid >> 6;
    const int wr   = w >> 1, wc = w & 1;
    const int lr   = lane & 31;
    const int lh   = lane >> 5;
    const int i0   = bx * 128;      // A rows
    const int j0   = by * 128;      // B rows (= output cols)

    f32x16 acc[2][2];
    #pragma unroll
    for (int g = 0; g < 2; ++g)
        #pragma unroll
        for (int h = 0; h < 2; ++h)
            #pragma unroll
            for (int e = 0; e < 16; ++e) acc[g][h][e] = 0.f;

    // per-lane fragment base pointers (row = .. + lr, k-offset = lh*8)
    const unsigned short* pa = xh + (size_t)(i0 + wr * 64 + lr) * DIM + lh * 8;
    const unsigned short* pb = xh + (size_t)(j0 + wc * 64 + lr) * DIM + lh * 8;

    #pragma unroll
    for (int ks = 0; ks < 8; ++ks) {
        const int ko = ks * 16;                  // same K order as staged version
        bf16x8 a[2], bb[2];
        a[0]  = *(const bf16x8*)&pa[ko];
        a[1]  = *(const bf16x8*)&pa[32 * DIM + ko];
        bb[0] = *(const bf16x8*)&pb[ko];
        bb[1] = *(const bf16x8*)&pb[32 * DIM + ko];
        #pragma unroll
        for (int g = 0; g < 2; ++g)
            #pragma unroll
            for (int h = 0; h < 2; ++h)
                acc[g][h] = __builtin_amdgcn_mfma_f32_32x32x16_bf16(
                    a[g], bb[h], acc[g][h], 0, 0, 0);
    }

    // ---- epilogue: d2 = sq_i + sq_j - 2*dot ; col-min AND row-min over negatives.
    const float FINF = __uint_as_float(0x7f800000u);
    float cminh[2] = {FINF, FINF};

    #pragma unroll
    for (int g = 0; g < 2; ++g) {
        float rmin[16];
        #pragma unroll
        for (int e = 0; e < 16; ++e) rmin[e] = FINF;

        #pragma unroll
        for (int h = 0; h < 2; ++h) {
            int colt = wc * 64 + h * 32 + lr;
            int j  = j0 + colt;
            int cj = comm[j];
            float sqj = sq[j];
            float cm = FINF;
            #pragma unroll
            for (int q = 0; q < 4; ++q) {
                int rb = i0 + wr * 64 + g * 32 + 4 * lh + 8 * q;
                int4   civ = *(const int4*)&comm[rb];
                float4 sqv = *(const float4*)&sq[rb];
                const int cvals[4] = {civ.x, civ.y, civ.z, civ.w};
                const float svals[4] = {sqv.x, sqv.y, sqv.z, sqv.w};
                #pragma unroll
                for (int t = 0; t < 4; ++t) {
                    float d2 = fmaxf(svals[t] + sqj - 2.f * acc[g][h][q * 4 + t], 0.f);
                    if (cvals[t] != cj) {
                        cm = fminf(cm, d2);
                        rmin[q * 4 + t] = fminf(rmin[q * 4 + t], d2);
                    }
                }
            }
            cminh[h] = fminf(cminh[h], cm);
        }

        // write this g's row-min partials; acc[g] now dead
        #pragma unroll
        for (int q = 0; q < 4; ++q)
            #pragma unroll
            for (int t = 0; t < 4; ++t) {
                int rowl = wr * 64 + g * 32 + 4 * lh + 8 * q + t;
                rowpart[rowl][wc * 32 + lr] = rmin[q * 4 + t];
            }
    }

    #pragma unroll
    for (int h = 0; h < 2; ++h)
        cminh[h] = fminf(cminh[h], __shfl_xor(cminh[h], 32));
    if (lh == 0) {
        #pragma unroll
        for (int h = 0; h < 2; ++h)
            colpart[wc * 64 + h * 32 + lr][wr] = cminh[h];
    }
    __syncthreads();
    if (tid < 128) {
        float m = FINF;
        #pragma unroll
        for (int k = 0; k < 16; ++k) {
            float4 vv = *(const float4*)&rowpart[tid][k * 4];
            m = fminf(m, fminf(fminf(vv.x, vv.y), fminf(vv.z, vv.w)));
        }
        float cm = fminf(colpart[tid][0], colpart[tid][1]);
        atomicMin(&min_d2[i0 + tid], __float_as_uint(m));
        atomicMin(&min_d2[j0 + tid], __float_as_uint(cm));
    }
}

// ---------------------------------------------------------------------------
// Kernel 2: positives (wave per 32x32 tile-pair, no LDS staging, plain bf16)
// + in-kernel finalize: the LAST pos block (device-scope done-counter)
// reduces the 100 community partials and writes the output.
__global__ __launch_bounds__(256)
void pos_wave_kernel(const unsigned short* __restrict__ xh,
                     const float* __restrict__ sq,
                     const unsigned int* __restrict__ min_d2,
                     const int* __restrict__ offs,
                     const int* __restrict__ members,
                     double* __restrict__ psum,
                     unsigned int* __restrict__ pcnt,
                     unsigned int* __restrict__ done,
                     float* __restrict__ out) {
    __shared__ double       sred[4];
    __shared__ unsigned int cred[4];
    __shared__ unsigned int lastflag;

    const int c    = blockIdx.x >> 2;                     // 4 blocks/community
    const int tid  = threadIdx.x;
    const int lane = tid & 63;
    const int w    = tid >> 6;
    const int lr   = lane & 31;
    const int lh   = lane >> 5;
    const int wsub = ((blockIdx.x & 3) << 2) | w;         // 0..15

    const int beg  = offs[c], end = offs[c + 1];
    const int size = end - beg;

    if (size > 0) {
        const int m = (size + 31) >> 5;                   // 32-row tiles

        float tsum = 0.f;
        unsigned int tcnt = 0u;

        for (int idx = wsub; idx < m * m; idx += 16) {
            int ti = idx / m, tj = idx - ti * m;
            int s0 = ti * 32, t0 = tj * 32;
            int slotA = s0 + lr, slotB = t0 + lr;
            int nodeA = members[beg + (slotA < size ? slotA : size - 1)];
            int nodeB = members[beg + (slotB < size ? slotB : size - 1)];

            // epilogue operands issued early to hide latency under the MFMA loop
            float sqa_own = sq[nodeA];
            unsigned mb = min_d2[nodeA];
            float mn_own = (mb == 0x7f800000u) ? -1.f
                         : sqrtf(fmaxf(__uint_as_float(mb), 0.f));
            float sqb = sq[nodeB];

            const unsigned short* pA = xh + (size_t)nodeA * DIM;
            const unsigned short* pB = xh + (size_t)nodeB * DIM;

            f32x16 a0;
            #pragma unroll
            for (int e = 0; e < 16; ++e) a0[e] = 0.f;

            #pragma unroll
            for (int ks = 0; ks < 8; ++ks) {
                const int ko = ks * 16 + lh * 8;
                bf16x8 av = *(const bf16x8*)&pA[ko];
                bf16x8 bv = *(const bf16x8*)&pB[ko];
                a0 = __builtin_amdgcn_mfma_f32_32x32x16_bf16(av, bv, a0, 0, 0, 0);
            }

            #pragma unroll
            for (int q = 0; q < 4; ++q)
                #pragma unroll
                for (int t = 0; t < 4; ++t) {
                    int r = 4 * lh + 8 * q + t;          // output row within tile
                    float sqa = __shfl(sqa_own, r);      // lane r holds row r's values
                    float mn  = __shfl(mn_own, r);
                    int e = q * 4 + t;
                    if ((s0 + r < size) && (slotB < size) &&
                        (s0 + r != slotB) && (mn >= 0.f)) {
                        float d2   = sqa + sqb - 2.f * a0[e];
                        float dist = sqrtf(fmaxf(d2, 0.f));
                        tsum += fmaxf(dist - mn + MARGIN, 0.f);
                        tcnt += 1u;
                    }
                }
        }

        #pragma unroll
        for (int off = 32; off > 0; off >>= 1) {
            tsum += __shfl_down(tsum, off);
            tcnt += __shfl_down(tcnt, off);
        }
        if (lane == 0 && tcnt > 0u) {
            atomicAdd(&psum[c], (double)tsum);
            atomicAdd(&pcnt[c], tcnt);
        }
    }

    // ---- last-block finalize (device-scope arrival counter)
    __syncthreads();             // all waves' psum/pcnt atomics issued
    if (tid == 0) {
        __threadfence();         // prior atomics visible before done-increment
        unsigned r = atomicAdd(done, 1u);
        lastflag = (r == NPOSBLK - 1u) ? 1u : 0u;
    }
    __syncthreads();
    if (lastflag) {
        double s = 0.0; unsigned int cc = 0u;
        for (int b2 = tid; b2 < N_COMM; b2 += 256) {
            s  += atomicAdd(&psum[b2], 0.0);        // coherent-point reads
            cc += atomicAdd(&pcnt[b2], 0u);
        }
        #pragma unroll
        for (int off = 32; off > 0; off >>= 1) {
            s  += __shfl_down(s, off);
            cc += __shfl_down(cc, off);
        }
        if (lane == 0) { sred[w] = s; cred[w] = cc; }
        __syncthreads();
        if (tid == 0) {
            double st = sred[0] + sred[1] + sred[2] + sred[3];
            unsigned int ct = cred[0] + cred[1] + cred[2] + cred[3];
            out[0] = (ct > 0u) ? (float)(st / (double)ct) : 0.f;
        }
    }
}

// ---------------------------------------------------------------------------
extern "C" void kernel_launch(void* const* d_in, const int* in_sizes, int n_in,
                              void* d_out, int out_size, void* d_ws, size_t ws_size,
                              hipStream_t stream) {
    const float* x    = (const float*)d_in[0];
    const int*   comm = (const int*)d_in[1];
    float*       out  = (float*)d_out;

    // workspace layout (bytes):
    //       0 float  sq[8192]           32768
    //   32768 uint   min_d2[8192]       32768
    //   65536 int    offs[101]            512 (padded)
    //   66048 int    members[8192]      32768
    //   98816 double psum[100]           1024 (padded)
    //   99840 uint   pcnt[100]            512 (padded)
    //  100352 uint   done[1]              512 (padded)
    //  100864 ushort xh[8192*128]     2097152   (total ~2.2 MB)
    char* ws = (char*)d_ws;
    float*          sq      = (float*)(ws);
    unsigned int*   min_d2  = (unsigned int*)(ws + 32768);
    int*            offs    = (int*)(ws + 65536);
    int*            members = (int*)(ws + 66048);
    double*         psum    = (double*)(ws + 98816);
    unsigned int*   pcnt    = (unsigned int*)(ws + 99840);
    unsigned int*   done    = (unsigned int*)(ws + 100352);
    unsigned short* xh      = (unsigned short*)(ws + 100864);

    prep_kernel<<<2049, 256, 0, stream>>>(x, comm, xh, sq, min_d2,
                                          offs, members, psum, pcnt, done);

    const int ntri = (N_NODES / 128) * (N_NODES / 128 + 1) / 2;   // 2080
    minneg_mfma_kernel<<<ntri, 256, 0, stream>>>(xh, comm, sq, min_d2);

    pos_wave_kernel<<<NPOSBLK, 256, 0, stream>>>(xh, sq, min_d2, offs,
                                                 members, psum, pcnt, done, out);
}

// Round 9
// 110.220 us; speedup vs baseline: 1.1709x; 1.1709x over previous
//
#include <hip/hip_runtime.h>

#define N_NODES 8192
#define DIM     128
#define N_COMM  100
#define MARGIN  1.0f
#define NPOSBLK (N_COMM * 4)

// X stored in MFMA-FRAGMENT ORDER (xhf): for panel p (rows 32p..32p+31) and
// slot s (k in [16s,16s+16)), a contiguous 1KB block holds lane l's bf16x8 at
// l*16: row 32p+(l&31), k = 16s+8*(l>>5)+i. A wave's 32x32x16 operand load is
// then ONE coalesced 1KB read (base+lane*16) straight from L2 (2MB resident).
// -> minneg has NO LDS staging, NO barriers in the K-loop, no bank conflicts.
// (Round-8 lesson: direct-global from ROW-major = 32 scattered 32B segments
// per load -> L2-request-bound, 2x slower. Fragment-order fixes coalescing.)
// (Round-5 lesson: cooperative grid.sync >>100us on MI355X — multi-kernel +
// device-scope done-counter merge for pos+finalize is the fastest structure.)
#define RP_STR   68               // row-min partial stride (floats)

typedef __attribute__((ext_vector_type(8)))  short bf16x8;
typedef __attribute__((ext_vector_type(16))) float f32x16;

__device__ inline unsigned short f32_to_bf16_rne(float f) {
    unsigned u = __float_as_uint(f);
    unsigned r = u + 0x7fffu + ((u >> 16) & 1u);
    return (unsigned short)(r >> 16);
}

// ---------------------------------------------------------------------------
// Kernel 0 (merged): blocks 0..2047 = bf16 convert (fragment-order store) +
// row sq norms + min_d2 init (wave per row); block 2048 = bucketing + zeroing.
__global__ __launch_bounds__(256)
void prep_kernel(const float* __restrict__ x,
                 const int* __restrict__ comm,
                 unsigned short* __restrict__ xhf,
                 float* __restrict__ sq,
                 unsigned int* __restrict__ min_d2,
                 int* __restrict__ offs,
                 int* __restrict__ members,
                 double* __restrict__ psum,
                 unsigned int* __restrict__ pcnt,
                 unsigned int* __restrict__ done) {
    __shared__ int scnt[N_COMM];
    __shared__ int scur[N_COMM];
    const int tid = threadIdx.x;

    if (blockIdx.x < 2048) {
        int row  = blockIdx.x * 4 + (tid >> 6);
        int lane = tid & 63;
        const float* p = x + (size_t)row * DIM;
        float v0 = p[lane], v1 = p[lane + 64];
        unsigned short h0 = f32_to_bf16_rne(v0), h1 = f32_to_bf16_rne(v1);
        // fragment-order dest for (row, k=lane) and (row, k=lane+64):
        // idx = ((row>>5)*8 + (k>>4))*512 + ((row&31) + 32*((k>>3)&1))*8 + (k&7)
        size_t e1 = ((size_t)(row >> 5) * 8 + (lane >> 4)) * 512
                  + ((size_t)((row & 31) + 32 * ((lane >> 3) & 1))) * 8
                  + (lane & 7);
        xhf[e1]        = h0;           // k = lane
        xhf[e1 + 2048] = h1;           // k = lane+64 -> slot +4 -> +4*512 shorts
        float s = v0 * v0 + v1 * v1;   // sq stays fp32-exact
        #pragma unroll
        for (int off = 32; off > 0; off >>= 1) s += __shfl_down(s, off);
        if (lane == 0) {
            sq[row] = s;
            min_d2[row] = 0x7f800000u;   // +inf bits
        }
        return;
    }

    // ---- bucketing block
    if (tid < N_COMM) {
        scnt[tid] = 0;
        psum[tid] = 0.0;      // pos kernel accumulates -> zero each launch
        pcnt[tid] = 0u;
    }
    if (tid == 0) *done = 0u;
    __syncthreads();
    for (int i = tid; i < N_NODES; i += 256) atomicAdd(&scnt[comm[i]], 1);
    __syncthreads();
    if (tid == 0) {
        int acc = 0;
        for (int c = 0; c < N_COMM; ++c) { scur[c] = acc; offs[c] = acc; acc += scnt[c]; }
        offs[N_COMM] = acc;
    }
    __syncthreads();
    for (int i = tid; i < N_NODES; i += 256) {
        int p = atomicAdd(&scur[comm[i]], 1);
        members[p] = i;
    }
}

// ---------------------------------------------------------------------------
// Kernel 1: MFMA X·X^T (plain bf16, fragment-order loads), triangular grid
// (2080 blocks), NO K-loop barriers/LDS. col-min AND row-min epilogue.
// C/D layout (m74/m101): col = lane&31, row = (reg&3) + 8*(reg>>2) + 4*(lane>>5).
__global__ __launch_bounds__(256, 4)
void minneg_mfma_kernel(const unsigned short* __restrict__ xhf,
                        const int* __restrict__ comm,
                        const float* __restrict__ sq,
                        unsigned int* __restrict__ min_d2) {
    __shared__ __align__(16) float rowpart[128][RP_STR];   // 34816 B
    __shared__ float colpart[128][2];                      //  1024 B

    // linear -> lower-triangle (bx >= by)
    const int b = blockIdx.x;
    int bx = (int)((sqrtf(8.f * (float)b + 1.f) - 1.f) * 0.5f);
    while ((bx + 1) * (bx + 2) / 2 <= b) ++bx;
    while (bx * (bx + 1) / 2 > b) --bx;
    const int by = b - bx * (bx + 1) / 2;

    const int tid  = threadIdx.x;
    const int lane = tid & 63;
    const int w    = tid >> 6;
    const int wr   = w >> 1, wc = w & 1;
    const int lr   = lane & 31;
    const int lh   = lane >> 5;
    const int i0   = bx * 128;      // A rows
    const int j0   = by * 128;      // B rows (= output cols)

    f32x16 acc[2][2];
    #pragma unroll
    for (int g = 0; g < 2; ++g)
        #pragma unroll
        for (int h = 0; h < 2; ++h)
            #pragma unroll
            for (int e = 0; e < 16; ++e) acc[g][h][e] = 0.f;

    // fragment base pointers: panel p block = (p*8+s)*512 shorts, +lane*8
    const int pA = bx * 4 + wr * 2;
    const int pB = by * 4 + wc * 2;
    const unsigned short* a0p = xhf + ((size_t)pA       * 8 * 512) + (size_t)lane * 8;
    const unsigned short* a1p = xhf + ((size_t)(pA + 1) * 8 * 512) + (size_t)lane * 8;
    const unsigned short* b0p = xhf + ((size_t)pB       * 8 * 512) + (size_t)lane * 8;
    const unsigned short* b1p = xhf + ((size_t)(pB + 1) * 8 * 512) + (size_t)lane * 8;

    #pragma unroll
    for (int ks = 0; ks < 8; ++ks) {          // same K order as staged version
        const int o = ks * 512;
        bf16x8 a0 = *(const bf16x8*)&a0p[o];
        bf16x8 a1 = *(const bf16x8*)&a1p[o];
        bf16x8 b0 = *(const bf16x8*)&b0p[o];
        bf16x8 b1 = *(const bf16x8*)&b1p[o];
        acc[0][0] = __builtin_amdgcn_mfma_f32_32x32x16_bf16(a0, b0, acc[0][0], 0, 0, 0);
        acc[0][1] = __builtin_amdgcn_mfma_f32_32x32x16_bf16(a0, b1, acc[0][1], 0, 0, 0);
        acc[1][0] = __builtin_amdgcn_mfma_f32_32x32x16_bf16(a1, b0, acc[1][0], 0, 0, 0);
        acc[1][1] = __builtin_amdgcn_mfma_f32_32x32x16_bf16(a1, b1, acc[1][1], 0, 0, 0);
    }

    // ---- epilogue: d2 = sq_i + sq_j - 2*dot ; col-min AND row-min over negatives.
    const float FINF = __uint_as_float(0x7f800000u);
    float cminh[2] = {FINF, FINF};

    #pragma unroll
    for (int g = 0; g < 2; ++g) {
        float rmin[16];
        #pragma unroll
        for (int e = 0; e < 16; ++e) rmin[e] = FINF;

        #pragma unroll
        for (int h = 0; h < 2; ++h) {
            int colt = wc * 64 + h * 32 + lr;
            int j  = j0 + colt;
            int cj = comm[j];
            float sqj = sq[j];
            float cm = FINF;
            #pragma unroll
            for (int q = 0; q < 4; ++q) {
                int rb = i0 + wr * 64 + g * 32 + 4 * lh + 8 * q;
                int4   civ = *(const int4*)&comm[rb];
                float4 sqv = *(const float4*)&sq[rb];
                const int cvals[4] = {civ.x, civ.y, civ.z, civ.w};
                const float svals[4] = {sqv.x, sqv.y, sqv.z, sqv.w};
                #pragma unroll
                for (int t = 0; t < 4; ++t) {
                    float d2 = fmaxf(svals[t] + sqj - 2.f * acc[g][h][q * 4 + t], 0.f);
                    if (cvals[t] != cj) {
                        cm = fminf(cm, d2);
                        rmin[q * 4 + t] = fminf(rmin[q * 4 + t], d2);
                    }
                }
            }
            cminh[h] = fminf(cminh[h], cm);
        }

        // write this g's row-min partials; acc[g] now dead
        #pragma unroll
        for (int q = 0; q < 4; ++q)
            #pragma unroll
            for (int t = 0; t < 4; ++t) {
                int rowl = wr * 64 + g * 32 + 4 * lh + 8 * q + t;
                rowpart[rowl][wc * 32 + lr] = rmin[q * 4 + t];
            }
    }

    #pragma unroll
    for (int h = 0; h < 2; ++h)
        cminh[h] = fminf(cminh[h], __shfl_xor(cminh[h], 32));
    if (lh == 0) {
        #pragma unroll
        for (int h = 0; h < 2; ++h)
            colpart[wc * 64 + h * 32 + lr][wr] = cminh[h];
    }
    __syncthreads();
    if (tid < 128) {
        float m = FINF;
        #pragma unroll
        for (int k = 0; k < 16; ++k) {
            float4 vv = *(const float4*)&rowpart[tid][k * 4];
            m = fminf(m, fminf(fminf(vv.x, vv.y), fminf(vv.z, vv.w)));
        }
        float cm = fminf(colpart[tid][0], colpart[tid][1]);
        atomicMin(&min_d2[i0 + tid], __float_as_uint(m));
        atomicMin(&min_d2[j0 + tid], __float_as_uint(cm));
    }
}

// ---------------------------------------------------------------------------
// Kernel 2: positives (wave per 32x32 tile-pair, fragment-order gathers)
// + in-kernel finalize via device-scope done-counter (last block reduces).
__global__ __launch_bounds__(256)
void pos_wave_kernel(const unsigned short* __restrict__ xhf,
                     const float* __restrict__ sq,
                     const unsigned int* __restrict__ min_d2,
                     const int* __restrict__ offs,
                     const int* __restrict__ members,
                     double* __restrict__ psum,
                     unsigned int* __restrict__ pcnt,
                     unsigned int* __restrict__ done,
                     float* __restrict__ out) {
    __shared__ double       sred[4];
    __shared__ unsigned int cred[4];
    __shared__ unsigned int lastflag;

    const int c    = blockIdx.x >> 2;                     // 4 blocks/community
    const int tid  = threadIdx.x;
    const int lane = tid & 63;
    const int w    = tid >> 6;
    const int lr   = lane & 31;
    const int lh   = lane >> 5;
    const int wsub = ((blockIdx.x & 3) << 2) | w;         // 0..15

    const int beg  = offs[c], end = offs[c + 1];
    const int size = end - beg;

    if (size > 0) {
        const int m = (size + 31) >> 5;                   // 32-row tiles

        float tsum = 0.f;
        unsigned int tcnt = 0u;

        for (int idx = wsub; idx < m * m; idx += 16) {
            int ti = idx / m, tj = idx - ti * m;
            int s0 = ti * 32, t0 = tj * 32;
            int slotA = s0 + lr, slotB = t0 + lr;
            int nodeA = members[beg + (slotA < size ? slotA : size - 1)];
            int nodeB = members[beg + (slotB < size ? slotB : size - 1)];

            // epilogue operands issued early to hide latency under the MFMA loop
            float sqa_own = sq[nodeA];
            unsigned mb = min_d2[nodeA];
            float mn_own = (mb == 0x7f800000u) ? -1.f
                         : sqrtf(fmaxf(__uint_as_float(mb), 0.f));
            float sqb = sq[nodeB];

            // fragment-order gather base: ((n>>5)*8 + ks)*512 + ((n&31)+32*lh)*8
            const unsigned short* pA = xhf + (size_t)(nodeA >> 5) * 4096
                                     + ((size_t)((nodeA & 31) + 32 * lh)) * 8;
            const unsigned short* pB = xhf + (size_t)(nodeB >> 5) * 4096
                                     + ((size_t)((nodeB & 31) + 32 * lh)) * 8;

            f32x16 a0;
            #pragma unroll
            for (int e = 0; e < 16; ++e) a0[e] = 0.f;

            #pragma unroll
            for (int ks = 0; ks < 8; ++ks) {
                bf16x8 av = *(const bf16x8*)&pA[ks * 512];
                bf16x8 bv = *(const bf16x8*)&pB[ks * 512];
                a0 = __builtin_amdgcn_mfma_f32_32x32x16_bf16(av, bv, a0, 0, 0, 0);
            }

            #pragma unroll
            for (int q = 0; q < 4; ++q)
                #pragma unroll
                for (int t = 0; t < 4; ++t) {
                    int r = 4 * lh + 8 * q + t;          // output row within tile
                    float sqa = __shfl(sqa_own, r);      // lane r holds row r's values
                    float mn  = __shfl(mn_own, r);
                    int e = q * 4 + t;
                    if ((s0 + r < size) && (slotB < size) &&
                        (s0 + r != slotB) && (mn >= 0.f)) {
                        float d2   = sqa + sqb - 2.f * a0[e];
                        float dist = sqrtf(fmaxf(d2, 0.f));
                        tsum += fmaxf(dist - mn + MARGIN, 0.f);
                        tcnt += 1u;
                    }
                }
        }

        #pragma unroll
        for (int off = 32; off > 0; off >>= 1) {
            tsum += __shfl_down(tsum, off);
            tcnt += __shfl_down(tcnt, off);
        }
        if (lane == 0 && tcnt > 0u) {
            atomicAdd(&psum[c], (double)tsum);
            atomicAdd(&pcnt[c], tcnt);
        }
    }

    // ---- last-block finalize (device-scope arrival counter)
    __syncthreads();             // all waves' psum/pcnt atomics issued
    if (tid == 0) {
        __threadfence();         // prior atomics visible before done-increment
        unsigned r = atomicAdd(done, 1u);
        lastflag = (r == NPOSBLK - 1u) ? 1u : 0u;
    }
    __syncthreads();
    if (lastflag) {
        double s = 0.0; unsigned int cc = 0u;
        for (int b2 = tid; b2 < N_COMM; b2 += 256) {
            s  += atomicAdd(&psum[b2], 0.0);        // coherent-point reads
            cc += atomicAdd(&pcnt[b2], 0u);
        }
        #pragma unroll
        for (int off = 32; off > 0; off >>= 1) {
            s  += __shfl_down(s, off);
            cc += __shfl_down(cc, off);
        }
        if (lane == 0) { sred[w] = s; cred[w] = cc; }
        __syncthreads();
        if (tid == 0) {
            double st = sred[0] + sred[1] + sred[2] + sred[3];
            unsigned int ct = cred[0] + cred[1] + cred[2] + cred[3];
            out[0] = (ct > 0u) ? (float)(st / (double)ct) : 0.f;
        }
    }
}

// ---------------------------------------------------------------------------
extern "C" void kernel_launch(void* const* d_in, const int* in_sizes, int n_in,
                              void* d_out, int out_size, void* d_ws, size_t ws_size,
                              hipStream_t stream) {
    const float* x    = (const float*)d_in[0];
    const int*   comm = (const int*)d_in[1];
    float*       out  = (float*)d_out;

    // workspace layout (bytes):
    //       0 float  sq[8192]           32768
    //   32768 uint   min_d2[8192]       32768
    //   65536 int    offs[101]            512 (padded)
    //   66048 int    members[8192]      32768
    //   98816 double psum[100]           1024 (padded)
    //   99840 uint   pcnt[100]            512 (padded)
    //  100352 uint   done[1]              512 (padded)
    //  100864 ushort xhf[8192*128]    2097152   (fragment-order; total ~2.2 MB)
    char* ws = (char*)d_ws;
    float*          sq      = (float*)(ws);
    unsigned int*   min_d2  = (unsigned int*)(ws + 32768);
    int*            offs    = (int*)(ws + 65536);
    int*            members = (int*)(ws + 66048);
    double*         psum    = (double*)(ws + 98816);
    unsigned int*   pcnt    = (unsigned int*)(ws + 99840);
    unsigned int*   done    = (unsigned int*)(ws + 100352);
    unsigned short* xhf     = (unsigned short*)(ws + 100864);

    prep_kernel<<<2049, 256, 0, stream>>>(x, comm, xhf, sq, min_d2,
                                          offs, members, psum, pcnt, done);

    const int ntri = (N_NODES / 128) * (N_NODES / 128 + 1) / 2;   // 2080
    minneg_mfma_kernel<<<ntri, 256, 0, stream>>>(xhf, comm, sq, min_d2);

    pos_wave_kernel<<<NPOSBLK, 256, 0, stream>>>(xhf, sq, min_d2, offs,
                                                 members, psum, pcnt, done, out);
}